// Round 9
// baseline (273.811 us; speedup 1.0000x reference)
//
#include <hip/hip_runtime.h>

#define F 64      // F_IN == F_OUT == 64
#define TILE 64   // nodes per tile / per fused block
#define CAP 2048  // bucket capacity (mean 1024 edges/tile, 32 sigma headroom)
#define PADC 68   // r-major agg row stride (68*4 = 272 B: 16B-aligned, bank-skewed)
#define CNTP 16   // tileCnt padding: one counter per 64B line (R4 lesson)
#define NT_MAX 1024
#define BIN_BLOCKS 256

// NOTE: packing assumes n_nodes < 65536 (problem fixes N=50000).
// entry = dst<<16 | src ; tile = dst>>6 ; local d = (entry>>16)&63.

// ---------------------------------------------------------------------------
// R8 (resubmit; prior bench died on container-acquisition infra error):
// (a) fused kernel LDS 38.4 -> 22.4 KB (drop xT staging, read x rows direct
// from L1; agg stored r-major so phase D writes ds_write_b128 and phase E
// reads ds_read_b128 — 512 b32 reads/thread -> 64 b128) for 6 blocks/CU;
// (b) bin grid 128 -> 256 blocks; (c) memset folded into prep kernel.
// ---------------------------------------------------------------------------

// prep: transpose W (WT[k][o] = W[o][k]) + zero tileCnt
__global__ __launch_bounds__(256) void prep_kernel(
    const float* __restrict__ W_rel, const float* __restrict__ W_root,
    float* __restrict__ WTrel, float* __restrict__ WTroot,
    int* __restrict__ tileCnt, int n_cnt) {
  const int idx = blockIdx.x * 256 + threadIdx.x;
  if (idx < F * F) {
    const int o = idx >> 6, k = idx & 63;
    WTrel[k * F + o] = W_rel[idx];
    WTroot[k * F + o] = W_root[idx];
  }
  for (int i = idx; i < n_cnt; i += gridDim.x * 256) tileCnt[i] = 0;
}

// Bin edges by 64-node tile via per-block region reservation (R7 scheme).
__global__ __launch_bounds__(256) void bin_kernel(
    const int* __restrict__ edge_index, int* __restrict__ tileCnt,
    unsigned* __restrict__ tileBuf, int n_edges, int n_tiles) {
  __shared__ int hist[NT_MAX];   // pass 1: counts; pass 2: local cursor
  __shared__ int gbase[NT_MAX];  // reserved global base per tile

  const int t = threadIdx.x;
  for (int i = t; i < n_tiles; i += 256) hist[i] = 0;
  __syncthreads();

  const int per = (n_edges + gridDim.x - 1) / gridDim.x;
  const int e0 = blockIdx.x * per;
  const int e1 = min(e0 + per, n_edges);

  for (int e = e0 + t; e < e1; e += 256)
    atomicAdd(&hist[edge_index[n_edges + e] >> 6], 1);
  __syncthreads();

  for (int i = t; i < n_tiles; i += 256) {
    const int c = hist[i];
    gbase[i] = (c > 0) ? atomicAdd(&tileCnt[i * CNTP], c) : 0;
    hist[i] = 0;  // becomes the local cursor
  }
  __syncthreads();

  for (int e = e0 + t; e < e1; e += 256) {
    const int src = edge_index[e];
    const int dst = edge_index[n_edges + e];
    const int tile = dst >> 6;
    const int pos = gbase[tile] + atomicAdd(&hist[tile], 1);
    if (pos < CAP)  // statistically never; guards bucket overflow corruption
      tileBuf[(size_t)tile * CAP + pos] =
          ((unsigned)dst << 16) | (unsigned)src;
  }
}

// ---------------------------------------------------------------------------
// Fused: in-LDS counting sort + dense gather + GEMM + bias + ReLU.
// LDS: agg[64][68] r-major (17.4 KB) + ssrc ushort (4.2 KB) + tables ~0.8 KB
// = 22.4 KB.  __launch_bounds__(256,6) -> 6 blocks/CU target.
// ---------------------------------------------------------------------------
__global__ __launch_bounds__(256, 6) void tile_sort_gather_gemm_kernel(
    const float* __restrict__ x,
    const float* __restrict__ WTrel,   // [F][F] k-major
    const float* __restrict__ b_rel,   // [F]
    const float* __restrict__ WTroot,  // [F][F] k-major
    const int* __restrict__ tileCnt,
    const unsigned* __restrict__ tileBuf,
    float* __restrict__ out, int n_nodes) {
  __shared__ float agg[TILE * PADC];        // r-major: agg[r*PADC + k]
  __shared__ unsigned short ssrc[CAP + 64]; // sorted-by-dst srcs (+64 pad)
  __shared__ int hist[TILE];
  __shared__ int soff[TILE + 1];
  __shared__ int scur[TILE];

  const int t = threadIdx.x;
  const int lane = t & 63;
  const int w = t >> 6;
  const int tile = blockIdx.x;
  const int node0 = tile * TILE;
  const int cnt = min(tileCnt[tile * CNTP], CAP);
  const unsigned* lst = tileBuf + (size_t)tile * CAP;

  // ---- phase 0: zero hist, zero ssrc pad region [cnt, cnt+64)
  if (t < TILE) hist[t] = 0;
  if (t < 64 && cnt + t < CAP + 64) ssrc[cnt + t] = 0;
  __syncthreads();

  // ---- phase A: histogram of local dsts (int LDS atomics)
  for (int i = t; i < cnt; i += 256) atomicAdd(&hist[(lst[i] >> 16) & 63], 1);
  __syncthreads();

  // ---- phase B: exclusive scan of 64 counters (wave 0, shfl_up)
  if (w == 0) {
    int v = hist[lane];
    int incl = v;
#pragma unroll
    for (int d = 1; d < 64; d <<= 1) {
      int up = __shfl_up(incl, d, 64);
      if (lane >= d) incl += up;
    }
    soff[lane] = incl - v;
    scur[lane] = incl - v;
    if (lane == 63) soff[64] = incl;  // == cnt
  }
  __syncthreads();

  // ---- phase C: counting-sort scatter (int LDS atomics)
  for (int i = t; i < cnt; i += 256) {
    const unsigned e = lst[i];
    const int d = (int)((e >> 16) & 63);
    const int pos = atomicAdd(&scur[d], 1);
    ssrc[pos] = (unsigned short)(e & 0xFFFFu);
  }
  __syncthreads();

  // ---- phase D: dense per-node gather (atomic-free, 4-deep float4 MLP);
  // lanes = 4 edge-slots x 16 feature-quads; result written r-major as one
  // ds_write_b128 per node (16 lanes x 16 B contiguous -> conflict-free).
  const int slot = lane >> 4;  // 0..3 edge slot
  const int fq = lane & 15;    // feature quad: features 4fq..4fq+3
#pragma unroll 2
  for (int nn = 0; nn < 16; ++nn) {
    const int d = w * 16 + nn;
    const int start = soff[d];
    const int end = soff[d + 1];
    float4 acc = make_float4(0.f, 0.f, 0.f, 0.f);
    const int i0 = slot, i1 = 4 + slot, i2 = 8 + slot, i3 = 12 + slot;
    for (int e0 = start; e0 < end; e0 += 16) {
      const int m = end - e0;  // lanes with i < m are valid this chunk
      // invalid lanes read ssrc[cnt] == 0 (pad), adds are masked below
      const int j0 = (i0 < m) ? e0 + i0 : cnt;
      const int j1 = (i1 < m) ? e0 + i1 : cnt;
      const int j2 = (i2 < m) ? e0 + i2 : cnt;
      const int j3 = (i3 < m) ? e0 + i3 : cnt;
      const int s0 = (int)ssrc[j0];
      const int s1 = (int)ssrc[j1];
      const int s2 = (int)ssrc[j2];
      const int s3 = (int)ssrc[j3];
      const float4 f0 = *(const float4*)(x + (size_t)s0 * F + fq * 4);
      const float4 f1 = *(const float4*)(x + (size_t)s1 * F + fq * 4);
      const float4 f2 = *(const float4*)(x + (size_t)s2 * F + fq * 4);
      const float4 f3 = *(const float4*)(x + (size_t)s3 * F + fq * 4);
      acc.x += (i0 < m ? f0.x : 0.f); acc.y += (i0 < m ? f0.y : 0.f);
      acc.z += (i0 < m ? f0.z : 0.f); acc.w += (i0 < m ? f0.w : 0.f);
      acc.x += (i1 < m ? f1.x : 0.f); acc.y += (i1 < m ? f1.y : 0.f);
      acc.z += (i1 < m ? f1.z : 0.f); acc.w += (i1 < m ? f1.w : 0.f);
      acc.x += (i2 < m ? f2.x : 0.f); acc.y += (i2 < m ? f2.y : 0.f);
      acc.z += (i2 < m ? f2.z : 0.f); acc.w += (i2 < m ? f2.w : 0.f);
      acc.x += (i3 < m ? f3.x : 0.f); acc.y += (i3 < m ? f3.y : 0.f);
      acc.z += (i3 < m ? f3.z : 0.f); acc.w += (i3 < m ? f3.w : 0.f);
    }
    // reduce the 4 slots
    acc.x += __shfl_xor(acc.x, 16, 64); acc.y += __shfl_xor(acc.y, 16, 64);
    acc.z += __shfl_xor(acc.z, 16, 64); acc.w += __shfl_xor(acc.w, 16, 64);
    acc.x += __shfl_xor(acc.x, 32, 64); acc.y += __shfl_xor(acc.y, 32, 64);
    acc.z += __shfl_xor(acc.z, 32, 64); acc.w += __shfl_xor(acc.w, 32, 64);
    if (slot == 0) *(float4*)&agg[d * PADC + fq * 4] = acc;
  }
  __syncthreads();

  // ---- phase E: out[r][o] = relu(b[o] + sum_k agg[r][k]*WTrel[k][o]
  //                                       + sum_k x[r][k]*WTroot[k][o])
  // x rows read directly from global (L1 broadcast; clamped for tail tile —
  // writes are guarded so clamped rows never reach out[]).
  const int oq = t & 15, rq = t >> 4;
  const int o0 = oq * 4, r0 = rq * 4;
  const float* xp0 = x + (size_t)min(node0 + r0 + 0, n_nodes - 1) * F;
  const float* xp1 = x + (size_t)min(node0 + r0 + 1, n_nodes - 1) * F;
  const float* xp2 = x + (size_t)min(node0 + r0 + 2, n_nodes - 1) * F;
  const float* xp3 = x + (size_t)min(node0 + r0 + 3, n_nodes - 1) * F;
  const float4 bias = *(const float4*)(b_rel + o0);
  float acc[4][4];
#pragma unroll
  for (int ri = 0; ri < 4; ++ri) {
    acc[ri][0] = bias.x; acc[ri][1] = bias.y;
    acc[ri][2] = bias.z; acc[ri][3] = bias.w;
  }
#pragma unroll 4
  for (int k0 = 0; k0 < F; k0 += 4) {
    const float4 a0 = *(const float4*)&agg[(r0 + 0) * PADC + k0];
    const float4 a1 = *(const float4*)&agg[(r0 + 1) * PADC + k0];
    const float4 a2 = *(const float4*)&agg[(r0 + 2) * PADC + k0];
    const float4 a3 = *(const float4*)&agg[(r0 + 3) * PADC + k0];
    const float4 q0 = *(const float4*)(xp0 + k0);
    const float4 q1 = *(const float4*)(xp1 + k0);
    const float4 q2 = *(const float4*)(xp2 + k0);
    const float4 q3 = *(const float4*)(xp3 + k0);
#pragma unroll
    for (int kk = 0; kk < 4; ++kk) {
      const float4 wr = *(const float4*)(WTrel + (k0 + kk) * F + o0);
      const float4 wo = *(const float4*)(WTroot + (k0 + kk) * F + o0);
      const float aa0 = ((const float*)&a0)[kk], xx0 = ((const float*)&q0)[kk];
      const float aa1 = ((const float*)&a1)[kk], xx1 = ((const float*)&q1)[kk];
      const float aa2 = ((const float*)&a2)[kk], xx2 = ((const float*)&q2)[kk];
      const float aa3 = ((const float*)&a3)[kk], xx3 = ((const float*)&q3)[kk];
      acc[0][0] += aa0 * wr.x + xx0 * wo.x; acc[0][1] += aa0 * wr.y + xx0 * wo.y;
      acc[0][2] += aa0 * wr.z + xx0 * wo.z; acc[0][3] += aa0 * wr.w + xx0 * wo.w;
      acc[1][0] += aa1 * wr.x + xx1 * wo.x; acc[1][1] += aa1 * wr.y + xx1 * wo.y;
      acc[1][2] += aa1 * wr.z + xx1 * wo.z; acc[1][3] += aa1 * wr.w + xx1 * wo.w;
      acc[2][0] += aa2 * wr.x + xx2 * wo.x; acc[2][1] += aa2 * wr.y + xx2 * wo.y;
      acc[2][2] += aa2 * wr.z + xx2 * wo.z; acc[2][3] += aa2 * wr.w + xx2 * wo.w;
      acc[3][0] += aa3 * wr.x + xx3 * wo.x; acc[3][1] += aa3 * wr.y + xx3 * wo.y;
      acc[3][2] += aa3 * wr.z + xx3 * wo.z; acc[3][3] += aa3 * wr.w + xx3 * wo.w;
    }
  }
#pragma unroll
  for (int ri = 0; ri < 4; ++ri) {
    const int gi = node0 + r0 + ri;
    if (gi < n_nodes) {
      float4 o4;
      o4.x = fmaxf(acc[ri][0], 0.f); o4.y = fmaxf(acc[ri][1], 0.f);
      o4.z = fmaxf(acc[ri][2], 0.f); o4.w = fmaxf(acc[ri][3], 0.f);
      *(float4*)(out + (size_t)gi * F + o0) = o4;
    }
  }
}

extern "C" void kernel_launch(void* const* d_in, const int* in_sizes, int n_in,
                              void* d_out, int out_size, void* d_ws, size_t ws_size,
                              hipStream_t stream) {
  const float* x      = (const float*)d_in[0];  // [N, 64]
  const float* W_rel  = (const float*)d_in[1];  // [64, 64]
  const float* b_rel  = (const float*)d_in[2];  // [64]
  const float* W_root = (const float*)d_in[3];  // [64, 64]
  const int* edge_index = (const int*)d_in[4];  // [2, E]

  const int n_nodes = in_sizes[0] / F;
  const int n_edges = in_sizes[4] / 2;
  const int n_tiles = (n_nodes + TILE - 1) / TILE;  // 782

  // workspace: tileCnt[n_tiles*16] (50 KB) + tileBuf (6.4 MB) + WT (32 KB)
  int* tileCnt      = (int*)d_ws;
  unsigned* tileBuf = (unsigned*)(tileCnt + (size_t)n_tiles * CNTP);
  float* WTrel      = (float*)(tileBuf + (size_t)n_tiles * CAP);
  float* WTroot     = WTrel + F * F;

  float* out = (float*)d_out;

  const int n_cnt = n_tiles * CNTP;
  const int gPrep = (n_cnt + 255) / 256;  // covers both transpose and zeroing
  prep_kernel<<<gPrep, 256, 0, stream>>>(W_rel, W_root, WTrel, WTroot,
                                         tileCnt, n_cnt);

  bin_kernel<<<BIN_BLOCKS, 256, 0, stream>>>(edge_index, tileCnt, tileBuf,
                                             n_edges, n_tiles);

  tile_sort_gather_gemm_kernel<<<n_tiles, 256, 0, stream>>>(
      x, WTrel, b_rel, WTroot, tileCnt, tileBuf, out, n_nodes);
}

// Round 10
// 196.322 us; speedup vs baseline: 1.3947x; 1.3947x over previous
//
#include <hip/hip_runtime.h>

#define F 64      // F_IN == F_OUT == 64
#define TILE 64   // nodes per tile / per fused block
#define CAP 2048  // bucket capacity (mean 1024 edges/tile, 32 sigma headroom)
#define PADC 68   // r-major agg row stride (68*4 = 272 B: 16B-aligned, bank-skewed)
#define CNTP 16   // tileCnt padding: one counter per 64B line (R4 lesson)
#define NT_MAX 1024
#define BIN_BLOCKS 256

// NOTE: packing assumes n_nodes < 65536 (problem fixes N=50000).
// entry = dst<<16 | src ; tile = dst>>6 ; local d = (entry>>16)&63.

// ---------------------------------------------------------------------------
// R9 -> R10: __launch_bounds__(256,6) forced an ~85-VGPR budget -> compiler
// spilled phase-E accumulators to scratch (WRITE_SIZE 12.5 -> 396 MB,
// FETCH 78 -> 262 MB, 3.5x regression).  Relax to (256,4): VGPR cap 128 >
// ~100 live set -> no spill; occupancy bounded by LDS/VGPR naturally
// (~5 blocks/CU at 22.5 KB LDS, ~100 VGPR).
// ---------------------------------------------------------------------------

// prep: transpose W (WT[k][o] = W[o][k]) + zero tileCnt
__global__ __launch_bounds__(256) void prep_kernel(
    const float* __restrict__ W_rel, const float* __restrict__ W_root,
    float* __restrict__ WTrel, float* __restrict__ WTroot,
    int* __restrict__ tileCnt, int n_cnt) {
  const int idx = blockIdx.x * 256 + threadIdx.x;
  if (idx < F * F) {
    const int o = idx >> 6, k = idx & 63;
    WTrel[k * F + o] = W_rel[idx];
    WTroot[k * F + o] = W_root[idx];
  }
  for (int i = idx; i < n_cnt; i += gridDim.x * 256) tileCnt[i] = 0;
}

// Bin edges by 64-node tile via per-block region reservation (R7 scheme).
__global__ __launch_bounds__(256) void bin_kernel(
    const int* __restrict__ edge_index, int* __restrict__ tileCnt,
    unsigned* __restrict__ tileBuf, int n_edges, int n_tiles) {
  __shared__ int hist[NT_MAX];   // pass 1: counts; pass 2: local cursor
  __shared__ int gbase[NT_MAX];  // reserved global base per tile

  const int t = threadIdx.x;
  for (int i = t; i < n_tiles; i += 256) hist[i] = 0;
  __syncthreads();

  const int per = (n_edges + gridDim.x - 1) / gridDim.x;
  const int e0 = blockIdx.x * per;
  const int e1 = min(e0 + per, n_edges);

  for (int e = e0 + t; e < e1; e += 256)
    atomicAdd(&hist[edge_index[n_edges + e] >> 6], 1);
  __syncthreads();

  for (int i = t; i < n_tiles; i += 256) {
    const int c = hist[i];
    gbase[i] = (c > 0) ? atomicAdd(&tileCnt[i * CNTP], c) : 0;
    hist[i] = 0;  // becomes the local cursor
  }
  __syncthreads();

  for (int e = e0 + t; e < e1; e += 256) {
    const int src = edge_index[e];
    const int dst = edge_index[n_edges + e];
    const int tile = dst >> 6;
    const int pos = gbase[tile] + atomicAdd(&hist[tile], 1);
    if (pos < CAP)  // statistically never; guards bucket overflow corruption
      tileBuf[(size_t)tile * CAP + pos] =
          ((unsigned)dst << 16) | (unsigned)src;
  }
}

// ---------------------------------------------------------------------------
// Fused: in-LDS counting sort + dense gather + GEMM + bias + ReLU.
// LDS: agg[64][68] r-major (17.4 KB) + ssrc ushort (4.2 KB) + tables ~0.8 KB
// = 22.4 KB.  __launch_bounds__(256,4): VGPR cap 128 — NO SPILL (R9 lesson:
// (256,6) -> 85-VGPR cap -> accumulator spill -> 396 MB scratch writes).
// ---------------------------------------------------------------------------
__global__ __launch_bounds__(256, 4) void tile_sort_gather_gemm_kernel(
    const float* __restrict__ x,
    const float* __restrict__ WTrel,   // [F][F] k-major
    const float* __restrict__ b_rel,   // [F]
    const float* __restrict__ WTroot,  // [F][F] k-major
    const int* __restrict__ tileCnt,
    const unsigned* __restrict__ tileBuf,
    float* __restrict__ out, int n_nodes) {
  __shared__ float agg[TILE * PADC];        // r-major: agg[r*PADC + k]
  __shared__ unsigned short ssrc[CAP + 64]; // sorted-by-dst srcs (+64 pad)
  __shared__ int hist[TILE];
  __shared__ int soff[TILE + 1];
  __shared__ int scur[TILE];

  const int t = threadIdx.x;
  const int lane = t & 63;
  const int w = t >> 6;
  const int tile = blockIdx.x;
  const int node0 = tile * TILE;
  const int cnt = min(tileCnt[tile * CNTP], CAP);
  const unsigned* lst = tileBuf + (size_t)tile * CAP;

  // ---- phase 0: zero hist, zero ssrc pad region [cnt, cnt+64)
  if (t < TILE) hist[t] = 0;
  if (t < 64 && cnt + t < CAP + 64) ssrc[cnt + t] = 0;
  __syncthreads();

  // ---- phase A: histogram of local dsts (int LDS atomics)
  for (int i = t; i < cnt; i += 256) atomicAdd(&hist[(lst[i] >> 16) & 63], 1);
  __syncthreads();

  // ---- phase B: exclusive scan of 64 counters (wave 0, shfl_up)
  if (w == 0) {
    int v = hist[lane];
    int incl = v;
#pragma unroll
    for (int d = 1; d < 64; d <<= 1) {
      int up = __shfl_up(incl, d, 64);
      if (lane >= d) incl += up;
    }
    soff[lane] = incl - v;
    scur[lane] = incl - v;
    if (lane == 63) soff[64] = incl;  // == cnt
  }
  __syncthreads();

  // ---- phase C: counting-sort scatter (int LDS atomics)
  for (int i = t; i < cnt; i += 256) {
    const unsigned e = lst[i];
    const int d = (int)((e >> 16) & 63);
    const int pos = atomicAdd(&scur[d], 1);
    ssrc[pos] = (unsigned short)(e & 0xFFFFu);
  }
  __syncthreads();

  // ---- phase D: dense per-node gather (atomic-free, 4-deep float4 MLP);
  // lanes = 4 edge-slots x 16 feature-quads; result written r-major as one
  // ds_write_b128 per node (16 lanes x 16 B contiguous -> conflict-free).
  const int slot = lane >> 4;  // 0..3 edge slot
  const int fq = lane & 15;    // feature quad: features 4fq..4fq+3
#pragma unroll 2
  for (int nn = 0; nn < 16; ++nn) {
    const int d = w * 16 + nn;
    const int start = soff[d];
    const int end = soff[d + 1];
    float4 acc = make_float4(0.f, 0.f, 0.f, 0.f);
    const int i0 = slot, i1 = 4 + slot, i2 = 8 + slot, i3 = 12 + slot;
    for (int e0 = start; e0 < end; e0 += 16) {
      const int m = end - e0;  // lanes with i < m are valid this chunk
      // invalid lanes read ssrc[cnt] == 0 (pad), adds are masked below
      const int j0 = (i0 < m) ? e0 + i0 : cnt;
      const int j1 = (i1 < m) ? e0 + i1 : cnt;
      const int j2 = (i2 < m) ? e0 + i2 : cnt;
      const int j3 = (i3 < m) ? e0 + i3 : cnt;
      const int s0 = (int)ssrc[j0];
      const int s1 = (int)ssrc[j1];
      const int s2 = (int)ssrc[j2];
      const int s3 = (int)ssrc[j3];
      const float4 f0 = *(const float4*)(x + (size_t)s0 * F + fq * 4);
      const float4 f1 = *(const float4*)(x + (size_t)s1 * F + fq * 4);
      const float4 f2 = *(const float4*)(x + (size_t)s2 * F + fq * 4);
      const float4 f3 = *(const float4*)(x + (size_t)s3 * F + fq * 4);
      acc.x += (i0 < m ? f0.x : 0.f); acc.y += (i0 < m ? f0.y : 0.f);
      acc.z += (i0 < m ? f0.z : 0.f); acc.w += (i0 < m ? f0.w : 0.f);
      acc.x += (i1 < m ? f1.x : 0.f); acc.y += (i1 < m ? f1.y : 0.f);
      acc.z += (i1 < m ? f1.z : 0.f); acc.w += (i1 < m ? f1.w : 0.f);
      acc.x += (i2 < m ? f2.x : 0.f); acc.y += (i2 < m ? f2.y : 0.f);
      acc.z += (i2 < m ? f2.z : 0.f); acc.w += (i2 < m ? f2.w : 0.f);
      acc.x += (i3 < m ? f3.x : 0.f); acc.y += (i3 < m ? f3.y : 0.f);
      acc.z += (i3 < m ? f3.z : 0.f); acc.w += (i3 < m ? f3.w : 0.f);
    }
    // reduce the 4 slots
    acc.x += __shfl_xor(acc.x, 16, 64); acc.y += __shfl_xor(acc.y, 16, 64);
    acc.z += __shfl_xor(acc.z, 16, 64); acc.w += __shfl_xor(acc.w, 16, 64);
    acc.x += __shfl_xor(acc.x, 32, 64); acc.y += __shfl_xor(acc.y, 32, 64);
    acc.z += __shfl_xor(acc.z, 32, 64); acc.w += __shfl_xor(acc.w, 32, 64);
    if (slot == 0) *(float4*)&agg[d * PADC + fq * 4] = acc;
  }
  __syncthreads();

  // ---- phase E: out[r][o] = relu(b[o] + sum_k agg[r][k]*WTrel[k][o]
  //                                       + sum_k x[r][k]*WTroot[k][o])
  // x rows read directly from global (L1 broadcast; clamped for tail tile —
  // writes are guarded so clamped rows never reach out[]).
  const int oq = t & 15, rq = t >> 4;
  const int o0 = oq * 4, r0 = rq * 4;
  const float* xp0 = x + (size_t)min(node0 + r0 + 0, n_nodes - 1) * F;
  const float* xp1 = x + (size_t)min(node0 + r0 + 1, n_nodes - 1) * F;
  const float* xp2 = x + (size_t)min(node0 + r0 + 2, n_nodes - 1) * F;
  const float* xp3 = x + (size_t)min(node0 + r0 + 3, n_nodes - 1) * F;
  const float4 bias = *(const float4*)(b_rel + o0);
  float acc[4][4];
#pragma unroll
  for (int ri = 0; ri < 4; ++ri) {
    acc[ri][0] = bias.x; acc[ri][1] = bias.y;
    acc[ri][2] = bias.z; acc[ri][3] = bias.w;
  }
#pragma unroll 4
  for (int k0 = 0; k0 < F; k0 += 4) {
    const float4 a0 = *(const float4*)&agg[(r0 + 0) * PADC + k0];
    const float4 a1 = *(const float4*)&agg[(r0 + 1) * PADC + k0];
    const float4 a2 = *(const float4*)&agg[(r0 + 2) * PADC + k0];
    const float4 a3 = *(const float4*)&agg[(r0 + 3) * PADC + k0];
    const float4 q0 = *(const float4*)(xp0 + k0);
    const float4 q1 = *(const float4*)(xp1 + k0);
    const float4 q2 = *(const float4*)(xp2 + k0);
    const float4 q3 = *(const float4*)(xp3 + k0);
#pragma unroll
    for (int kk = 0; kk < 4; ++kk) {
      const float4 wr = *(const float4*)(WTrel + (k0 + kk) * F + o0);
      const float4 wo = *(const float4*)(WTroot + (k0 + kk) * F + o0);
      const float aa0 = ((const float*)&a0)[kk], xx0 = ((const float*)&q0)[kk];
      const float aa1 = ((const float*)&a1)[kk], xx1 = ((const float*)&q1)[kk];
      const float aa2 = ((const float*)&a2)[kk], xx2 = ((const float*)&q2)[kk];
      const float aa3 = ((const float*)&a3)[kk], xx3 = ((const float*)&q3)[kk];
      acc[0][0] += aa0 * wr.x + xx0 * wo.x; acc[0][1] += aa0 * wr.y + xx0 * wo.y;
      acc[0][2] += aa0 * wr.z + xx0 * wo.z; acc[0][3] += aa0 * wr.w + xx0 * wo.w;
      acc[1][0] += aa1 * wr.x + xx1 * wo.x; acc[1][1] += aa1 * wr.y + xx1 * wo.y;
      acc[1][2] += aa1 * wr.z + xx1 * wo.z; acc[1][3] += aa1 * wr.w + xx1 * wo.w;
      acc[2][0] += aa2 * wr.x + xx2 * wo.x; acc[2][1] += aa2 * wr.y + xx2 * wo.y;
      acc[2][2] += aa2 * wr.z + xx2 * wo.z; acc[2][3] += aa2 * wr.w + xx2 * wo.w;
      acc[3][0] += aa3 * wr.x + xx3 * wo.x; acc[3][1] += aa3 * wr.y + xx3 * wo.y;
      acc[3][2] += aa3 * wr.z + xx3 * wo.z; acc[3][3] += aa3 * wr.w + xx3 * wo.w;
    }
  }
#pragma unroll
  for (int ri = 0; ri < 4; ++ri) {
    const int gi = node0 + r0 + ri;
    if (gi < n_nodes) {
      float4 o4;
      o4.x = fmaxf(acc[ri][0], 0.f); o4.y = fmaxf(acc[ri][1], 0.f);
      o4.z = fmaxf(acc[ri][2], 0.f); o4.w = fmaxf(acc[ri][3], 0.f);
      *(float4*)(out + (size_t)gi * F + o0) = o4;
    }
  }
}

extern "C" void kernel_launch(void* const* d_in, const int* in_sizes, int n_in,
                              void* d_out, int out_size, void* d_ws, size_t ws_size,
                              hipStream_t stream) {
  const float* x      = (const float*)d_in[0];  // [N, 64]
  const float* W_rel  = (const float*)d_in[1];  // [64, 64]
  const float* b_rel  = (const float*)d_in[2];  // [64]
  const float* W_root = (const float*)d_in[3];  // [64, 64]
  const int* edge_index = (const int*)d_in[4];  // [2, E]

  const int n_nodes = in_sizes[0] / F;
  const int n_edges = in_sizes[4] / 2;
  const int n_tiles = (n_nodes + TILE - 1) / TILE;  // 782

  // workspace: tileCnt[n_tiles*16] (50 KB) + tileBuf (6.4 MB) + WT (32 KB)
  int* tileCnt      = (int*)d_ws;
  unsigned* tileBuf = (unsigned*)(tileCnt + (size_t)n_tiles * CNTP);
  float* WTrel      = (float*)(tileBuf + (size_t)n_tiles * CAP);
  float* WTroot     = WTrel + F * F;

  float* out = (float*)d_out;

  const int n_cnt = n_tiles * CNTP;
  const int gPrep = (n_cnt + 255) / 256;  // covers both transpose and zeroing
  prep_kernel<<<gPrep, 256, 0, stream>>>(W_rel, W_root, WTrel, WTroot,
                                         tileCnt, n_cnt);

  bin_kernel<<<BIN_BLOCKS, 256, 0, stream>>>(edge_index, tileCnt, tileBuf,
                                             n_edges, n_tiles);

  tile_sort_gather_gemm_kernel<<<n_tiles, 256, 0, stream>>>(
      x, WTrel, b_rel, WTroot, tileCnt, tileBuf, out, n_nodes);
}

// Round 14
// 143.484 us; speedup vs baseline: 1.9083x; 1.3683x over previous
//
#include <hip/hip_runtime.h>

// GraphConv fused pipeline, v2 composition.
// Every piece here has individually passed a clean bench:
//  - fused tile kernel: R7 structure verbatim (52 us, 60 VGPR, no spill)
//  - prep (transpose+zero) and 256-block region-reservation binner: ran in
//    R9/R10 (those rounds' regressions were fused-kernel spill only)
// Constructs deliberately avoided: __launch_bounds__ min-waves arg (spill:
// R9 396 MB / R10 156 MB scratch) and `#pragma unroll 1` (present in all
// three container-failure rounds R11-R13, absent from every round that ran).

#define FEAT 64     // feature dim (F_IN == F_OUT)
#define TNODES 64   // nodes per destination tile
#define TCAP 2048   // per-tile bucket capacity (mean 1024, ~32 sigma margin)
#define KPAD 65     // k-major LDS row stride (floats)
#define CSTR 16     // tile counter stride: one counter per 64 B line
#define TMAX 1024   // max tiles in binner LDS tables
#define GBIN 256    // binner grid

// prep: WT[k][o] = W[o][k] for both weight matrices + zero tile counters
__global__ __launch_bounds__(256) void gcv2_prep(
    const float* __restrict__ W_rel, const float* __restrict__ W_root,
    float* __restrict__ WTrel, float* __restrict__ WTroot,
    int* __restrict__ tcnt, int n_cnt) {
  const int idx = blockIdx.x * 256 + threadIdx.x;
  if (idx < FEAT * FEAT) {
    const int o = idx >> 6, k = idx & 63;
    WTrel[k * FEAT + o] = W_rel[idx];
    WTroot[k * FEAT + o] = W_root[idx];
  }
  for (int i = idx; i < n_cnt; i += gridDim.x * 256) tcnt[i] = 0;
}

// binner: per-block LDS histogram -> one global atomic per (block,tile)
// region reservation -> dense packed writes (kills partial-line writeback).
// entry = dst<<16 | src  (valid since n_nodes = 50000 < 65536)
__global__ __launch_bounds__(256) void gcv2_bin(
    const int* __restrict__ eidx, int* __restrict__ tcnt,
    unsigned* __restrict__ tbuf, int n_edges, int n_tiles) {
  __shared__ int bh[TMAX];
  __shared__ int bbase[TMAX];

  const int t = threadIdx.x;
  for (int i = t; i < n_tiles; i += 256) bh[i] = 0;
  __syncthreads();

  const int per = (n_edges + gridDim.x - 1) / gridDim.x;
  const int e0 = blockIdx.x * per;
  const int e1 = min(e0 + per, n_edges);

  for (int e = e0 + t; e < e1; e += 256)
    atomicAdd(&bh[eidx[n_edges + e] >> 6], 1);
  __syncthreads();

  for (int i = t; i < n_tiles; i += 256) {
    const int c = bh[i];
    bbase[i] = (c > 0) ? atomicAdd(&tcnt[i * CSTR], c) : 0;
    bh[i] = 0;
  }
  __syncthreads();

  for (int e = e0 + t; e < e1; e += 256) {
    const int s = eidx[e];
    const int d = eidx[n_edges + e];
    const int tl = d >> 6;
    const int p = bbase[tl] + atomicAdd(&bh[tl], 1);
    if (p < TCAP)
      tbuf[(size_t)tl * TCAP + p] = ((unsigned)d << 16) | (unsigned)s;
  }
}

// fused per-tile: in-LDS counting sort by local dst -> atomic-free dense
// gather (4-deep float4 MLP + shfl_xor slot-reduce) -> register-blocked
// GEMM + bias + ReLU.  k-major LDS tiles, scalar phase-E reads (R7 layout).
__global__ __launch_bounds__(256) void gcv2_main(
    const float* __restrict__ x,
    const float* __restrict__ WTrel,   // [FEAT][FEAT] k-major
    const float* __restrict__ b_rel,   // [FEAT]
    const float* __restrict__ WTroot,  // [FEAT][FEAT] k-major
    const int* __restrict__ tcnt,
    const unsigned* __restrict__ tbuf,
    float* __restrict__ out, int n_nodes) {
  __shared__ float aggT[FEAT * KPAD];         // k-major: aggT[k*KPAD + r]
  __shared__ float xT[FEAT * KPAD];           // k-major self tile
  __shared__ unsigned short srcs[TCAP + 64];  // dst-sorted srcs (+pad)
  __shared__ int sh[TNODES];
  __shared__ int soff[TNODES + 1];
  __shared__ int scur[TNODES];

  const int t = threadIdx.x;
  const int lane = t & 63;
  const int w = t >> 6;
  const int tile = blockIdx.x;
  const int node0 = tile * TNODES;
  const int cnt = min(tcnt[tile * CSTR], TCAP);
  const unsigned* lst = tbuf + (size_t)tile * TCAP;

  // phase 0: zero histogram, zero srcs pad, stage xT (k-major)
  if (t < TNODES) sh[t] = 0;
  if (t < 64 && cnt + t < TCAP + 64) srcs[cnt + t] = 0;
  {
    const int c4 = t & 15;
    const int rr = t >> 4;
#pragma unroll
    for (int p = 0; p < 4; ++p) {
      const int r = p * 16 + rr;
      const int gi = node0 + r;
      float4 v = make_float4(0.f, 0.f, 0.f, 0.f);
      if (gi < n_nodes) v = *(const float4*)(x + (size_t)gi * FEAT + c4 * 4);
      xT[(c4 * 4 + 0) * KPAD + r] = v.x;
      xT[(c4 * 4 + 1) * KPAD + r] = v.y;
      xT[(c4 * 4 + 2) * KPAD + r] = v.z;
      xT[(c4 * 4 + 3) * KPAD + r] = v.w;
    }
  }
  __syncthreads();

  // phase A: histogram by local dst (int LDS atomics)
  for (int i = t; i < cnt; i += 256) atomicAdd(&sh[(lst[i] >> 16) & 63], 1);
  __syncthreads();

  // phase B: 64-wide exclusive scan in wave 0
  if (w == 0) {
    int v = sh[lane];
    int s = v;
#pragma unroll
    for (int d = 1; d < 64; d <<= 1) {
      int u = __shfl_up(s, d, 64);
      if (lane >= d) s += u;
    }
    soff[lane] = s - v;
    scur[lane] = s - v;
    if (lane == 63) soff[64] = s;  // == cnt
  }
  __syncthreads();

  // phase C: counting-sort scatter into srcs[]
  for (int i = t; i < cnt; i += 256) {
    const unsigned e = lst[i];
    const int d = (int)((e >> 16) & 63);
    srcs[atomicAdd(&scur[d], 1)] = (unsigned short)(e & 0xFFFFu);
  }
  __syncthreads();

  // phase D: dense per-node gather; lanes = 4 edge-slots x 16 feature-quads
  const int slot = lane >> 4;
  const int fq = lane & 15;
  for (int nn = 0; nn < 16; ++nn) {
    const int d = w * 16 + nn;
    const int jb = soff[d];
    const int je = soff[d + 1];
    float4 acc = make_float4(0.f, 0.f, 0.f, 0.f);
    const int i0 = slot, i1 = 4 + slot, i2 = 8 + slot, i3 = 12 + slot;
    for (int e0 = jb; e0 < je; e0 += 16) {
      const int m = je - e0;
      const int j0 = (i0 < m) ? e0 + i0 : cnt;  // pad slot -> src 0
      const int j1 = (i1 < m) ? e0 + i1 : cnt;
      const int j2 = (i2 < m) ? e0 + i2 : cnt;
      const int j3 = (i3 < m) ? e0 + i3 : cnt;
      const int s0 = (int)srcs[j0];
      const int s1 = (int)srcs[j1];
      const int s2 = (int)srcs[j2];
      const int s3 = (int)srcs[j3];
      const float4 f0 = *(const float4*)(x + (size_t)s0 * FEAT + fq * 4);
      const float4 f1 = *(const float4*)(x + (size_t)s1 * FEAT + fq * 4);
      const float4 f2 = *(const float4*)(x + (size_t)s2 * FEAT + fq * 4);
      const float4 f3 = *(const float4*)(x + (size_t)s3 * FEAT + fq * 4);
      acc.x += (i0 < m ? f0.x : 0.f); acc.y += (i0 < m ? f0.y : 0.f);
      acc.z += (i0 < m ? f0.z : 0.f); acc.w += (i0 < m ? f0.w : 0.f);
      acc.x += (i1 < m ? f1.x : 0.f); acc.y += (i1 < m ? f1.y : 0.f);
      acc.z += (i1 < m ? f1.z : 0.f); acc.w += (i1 < m ? f1.w : 0.f);
      acc.x += (i2 < m ? f2.x : 0.f); acc.y += (i2 < m ? f2.y : 0.f);
      acc.z += (i2 < m ? f2.z : 0.f); acc.w += (i2 < m ? f2.w : 0.f);
      acc.x += (i3 < m ? f3.x : 0.f); acc.y += (i3 < m ? f3.y : 0.f);
      acc.z += (i3 < m ? f3.z : 0.f); acc.w += (i3 < m ? f3.w : 0.f);
    }
    acc.x += __shfl_xor(acc.x, 16, 64); acc.y += __shfl_xor(acc.y, 16, 64);
    acc.z += __shfl_xor(acc.z, 16, 64); acc.w += __shfl_xor(acc.w, 16, 64);
    acc.x += __shfl_xor(acc.x, 32, 64); acc.y += __shfl_xor(acc.y, 32, 64);
    acc.z += __shfl_xor(acc.z, 32, 64); acc.w += __shfl_xor(acc.w, 32, 64);
    if (slot == 0) {
      aggT[(fq * 4 + 0) * KPAD + d] = acc.x;
      aggT[(fq * 4 + 1) * KPAD + d] = acc.y;
      aggT[(fq * 4 + 2) * KPAD + d] = acc.z;
      aggT[(fq * 4 + 3) * KPAD + d] = acc.w;
    }
  }
  __syncthreads();

  // phase E: out[r][o] = relu(b[o] + sum_k aggT[k][r]*WTrel[k][o]
  //                                  + sum_k xT[k][r]*WTroot[k][o])
  const int oq = t & 15, rq = t >> 4;
  const int o0 = oq * 4, r0 = rq * 4;
  const float4 bias = *(const float4*)(b_rel + o0);
  float acc[4][4];
#pragma unroll
  for (int ri = 0; ri < 4; ++ri) {
    acc[ri][0] = bias.x; acc[ri][1] = bias.y;
    acc[ri][2] = bias.z; acc[ri][3] = bias.w;
  }
#pragma unroll 4
  for (int k = 0; k < FEAT; ++k) {
    const float4 wr = *(const float4*)(WTrel + k * FEAT + o0);
    const float4 wo = *(const float4*)(WTroot + k * FEAT + o0);
    const float a0 = aggT[k * KPAD + r0 + 0], a1 = aggT[k * KPAD + r0 + 1];
    const float a2 = aggT[k * KPAD + r0 + 2], a3 = aggT[k * KPAD + r0 + 3];
    const float x0 = xT[k * KPAD + r0 + 0], x1 = xT[k * KPAD + r0 + 1];
    const float x2 = xT[k * KPAD + r0 + 2], x3 = xT[k * KPAD + r0 + 3];
    acc[0][0] += a0 * wr.x + x0 * wo.x; acc[0][1] += a0 * wr.y + x0 * wo.y;
    acc[0][2] += a0 * wr.z + x0 * wo.z; acc[0][3] += a0 * wr.w + x0 * wo.w;
    acc[1][0] += a1 * wr.x + x1 * wo.x; acc[1][1] += a1 * wr.y + x1 * wo.y;
    acc[1][2] += a1 * wr.z + x1 * wo.z; acc[1][3] += a1 * wr.w + x1 * wo.w;
    acc[2][0] += a2 * wr.x + x2 * wo.x; acc[2][1] += a2 * wr.y + x2 * wo.y;
    acc[2][2] += a2 * wr.z + x2 * wo.z; acc[2][3] += a2 * wr.w + x2 * wo.w;
    acc[3][0] += a3 * wr.x + x3 * wo.x; acc[3][1] += a3 * wr.y + x3 * wo.y;
    acc[3][2] += a3 * wr.z + x3 * wo.z; acc[3][3] += a3 * wr.w + x3 * wo.w;
  }
#pragma unroll
  for (int ri = 0; ri < 4; ++ri) {
    const int gi = node0 + r0 + ri;
    if (gi < n_nodes) {
      float4 o4;
      o4.x = fmaxf(acc[ri][0], 0.f); o4.y = fmaxf(acc[ri][1], 0.f);
      o4.z = fmaxf(acc[ri][2], 0.f); o4.w = fmaxf(acc[ri][3], 0.f);
      *(float4*)(out + (size_t)gi * FEAT + o0) = o4;
    }
  }
}

extern "C" void kernel_launch(void* const* d_in, const int* in_sizes, int n_in,
                              void* d_out, int out_size, void* d_ws, size_t ws_size,
                              hipStream_t stream) {
  const float* x      = (const float*)d_in[0];  // [N, 64]
  const float* W_rel  = (const float*)d_in[1];  // [64, 64]
  const float* b_rel  = (const float*)d_in[2];  // [64]
  const float* W_root = (const float*)d_in[3];  // [64, 64]
  const int* eidx     = (const int*)d_in[4];    // [2, E]

  const int n_nodes = in_sizes[0] / FEAT;
  const int n_edges = in_sizes[4] / 2;
  const int n_tiles = (n_nodes + TNODES - 1) / TNODES;  // 782

  int* tcnt      = (int*)d_ws;                                   // [n_tiles*CSTR]
  unsigned* tbuf = (unsigned*)(tcnt + (size_t)n_tiles * CSTR);   // [n_tiles*TCAP]
  float* WTrel   = (float*)(tbuf + (size_t)n_tiles * TCAP);
  float* WTroot  = WTrel + FEAT * FEAT;

  float* out = (float*)d_out;

  const int n_cnt = n_tiles * CSTR;
  const int gPrep = (n_cnt + 255) / 256;
  gcv2_prep<<<gPrep, 256, 0, stream>>>(W_rel, W_root, WTrel, WTroot, tcnt,
                                       n_cnt);

  gcv2_bin<<<GBIN, 256, 0, stream>>>(eidx, tcnt, tbuf, n_edges, n_tiles);

  gcv2_main<<<n_tiles, 256, 0, stream>>>(x, WTrel, b_rel, WTroot, tcnt, tbuf,
                                         out, n_nodes);
}